// Round 12
// baseline (406.382 us; speedup 1.0000x reference)
//
#include <hip/hip_runtime.h>
#include <stdint.h>

#define HH 1024
#define WW 2048
#define HWN (HH*WW)          // 2097152
#define BIGL HWN             // 'no cluster' sentinel
#define NSLOTS 26
#define MINCL 30
#define THREADS 256
#define LTHREADS 512         // k_local block size (8 waves)
#define MAXCAND 70000        // >= HWN/30 + 1
#define HSZ 512              // border_stats hash entries (256-pixel strip)
#define HSZ2 2048            // k_output hash entries (1024-pixel strip)
#define TILE 4096            // 64x64 tile
#define NTILES 512           // (1024/64)*(2048/64)
#define NB 128               // selection blocks

typedef int vi4 __attribute__((ext_vector_type(4)));
typedef unsigned long long u64;

// ---------------- global union-find (lock-free, min-root) ----------------
__device__ __forceinline__ int uf_load(int* p, int i) {
    return __hip_atomic_load(&p[i], __ATOMIC_RELAXED, __HIP_MEMORY_SCOPE_AGENT);
}
__device__ __forceinline__ void uf_store(int* p, int i, int v) {
    __hip_atomic_store(&p[i], v, __ATOMIC_RELAXED, __HIP_MEMORY_SCOPE_AGENT);
}
__device__ int uf_find(int* parent, int x) {
    int p = uf_load(parent, x);
    while (p != x) {
        int gp = uf_load(parent, p);
        if (gp != p) uf_store(parent, x, gp);   // path halving (benign race)
        x = p; p = gp;
    }
    return p;
}
__device__ void uf_union(int* parent, int a, int b) {
    int ra = uf_find(parent, a);
    int rb = uf_find(parent, b);
    while (ra != rb) {
        if (ra > rb) { int t = ra; ra = rb; rb = t; }   // hook larger under smaller
        int old = atomicCAS(&parent[rb], rb, ra);
        if (old == rb) return;
        rb = uf_find(parent, old);
        ra = uf_find(parent, ra);
    }
}

// ---------------- LDS union-find (block-local, min-root) ----------------
__device__ __forceinline__ int l_load(int* p, int i) {
    return __hip_atomic_load(&p[i], __ATOMIC_RELAXED, __HIP_MEMORY_SCOPE_WORKGROUP);
}
__device__ __forceinline__ void l_store(int* p, int i, int v) {
    __hip_atomic_store(&p[i], v, __ATOMIC_RELAXED, __HIP_MEMORY_SCOPE_WORKGROUP);
}
__device__ int l_find(int* lp, int x) {
    int p = l_load(lp, x);
    while (p != x) {
        int gp = l_load(lp, p);
        if (gp != p) l_store(lp, x, gp);
        x = p; p = gp;
    }
    return p;
}
__device__ void l_union(int* lp, int a, int b) {
    int ra = l_find(lp, a);
    int rb = l_find(lp, b);
    while (ra != rb) {
        if (ra > rb) { int t = ra; ra = rb; rb = t; }
        int old = atomicCAS(&lp[rb], rb, ra);
        if (old == rb) return;
        rb = l_find(lp, old);
        ra = l_find(lp, ra);
    }
}

// ---------------- fused init + per-tile CC + ws zeroing ----------------
__global__ __launch_bounds__(LTHREADS) void k_local(const float* __restrict__ mask,
                                                    uint8_t* __restrict__ flags,
                                                    int* __restrict__ parent,
                                                    int* __restrict__ sizes,
                                                    unsigned long long* __restrict__ colsum,
                                                    signed char* __restrict__ chan,
                                                    int* __restrict__ counter) {
    __shared__ uint8_t lact[66 * 72];   // halo active map, row stride 72
    __shared__ uint8_t lc8[TILE];
    __shared__ int lp[TILE];
    const int tid = threadIdx.x;
    int tile_x = blockIdx.x & 31, tile_y = blockIdx.x >> 5;
    int r0 = tile_y << 6, c0 = tile_x << 6;

    {   // zero this block's 1/512 slice of sizes/colsum/chan (+counter/done once)
        int base = blockIdx.x * (HWN / NTILES);      // 4096 elements
        vi4* sz4 = (vi4*)(sizes + base);
        vi4* cs4 = (vi4*)(colsum + base);
        for (int t = tid; t < 1024; t += LTHREADS) sz4[t] = (vi4)0;
        for (int t = tid; t < 2048; t += LTHREADS) cs4[t] = (vi4)0;
        vi4* ch4 = (vi4*)(chan + base);
        for (int t = tid; t < 256; t += LTHREADS) ch4[t] = (vi4)(-1);
        if (blockIdx.x == 0 && tid == 0) { counter[0] = 0; counter[1] = 0; }
    }

    {   // body rows: 64 rows x 16 float4, coalesced; 512 threads -> 2 passes
        int lr = tid >> 4, q = tid & 15;
        #pragma unroll
        for (int pass = 0; pass < 2; ++pass) {
            int rr = lr + pass * 32;
            const float4* src = (const float4*)(mask + (size_t)(r0 + rr) * WW + c0);
            float4 v = src[q];
            uint8_t* dst = &lact[(rr + 1) * 72 + (q * 4 + 1)];
            dst[0] = v.x > 0.1f; dst[1] = v.y > 0.1f;
            dst[2] = v.z > 0.1f; dst[3] = v.w > 0.1f;
        }
    }
    if (tid < 32) {          // halo top/bottom rows (cols 1..64)
        int q = tid & 15;
        bool top = tid < 16;
        int gr = top ? r0 - 1 : r0 + 64;
        int yy = top ? 0 : 65;
        uint8_t* dst = &lact[yy * 72 + (q * 4 + 1)];
        if ((unsigned)gr < HH) {
            const float4* src = (const float4*)(mask + (size_t)gr * WW + c0);
            float4 v = src[q];
            dst[0] = v.x > 0.1f; dst[1] = v.y > 0.1f;
            dst[2] = v.z > 0.1f; dst[3] = v.w > 0.1f;
        } else {
            dst[0] = 0; dst[1] = 0; dst[2] = 0; dst[3] = 0;
        }
    } else if (tid >= 64 && tid < 64 + 132) {   // halo cols incl corners
        int lane = tid - 64;                    // 0..131
        int side = lane >= 66;                  // 0=left(c0-1), 1=right(c0+64)
        int yy = side ? lane - 66 : lane;       // 0..65
        int gr = r0 - 1 + yy;
        int gc = side ? c0 + 64 : c0 - 1;
        bool a = false;
        if ((unsigned)gr < HH && (unsigned)gc < WW) a = mask[(size_t)gr * WW + gc] > 0.1f;
        lact[yy * 72 + (side ? 65 : 0)] = a ? 1 : 0;
    }
    __syncthreads();
    for (int li = tid; li < TILE; li += LTHREADS) {
        int lr = li >> 6, lc = li & 63;
        int b = (lr + 1) * 72 + (lc + 1);
        int a = lact[b];
        int cnt = lact[b - 73] + lact[b - 72] + lact[b - 71]
                + lact[b - 1]  + a           + lact[b + 1]
                + lact[b + 71] + lact[b + 72] + lact[b + 73];
        lc8[li] = (uint8_t)(a | ((a && cnt >= 4) ? 2 : 0));  // MIN_SAMPLES=4 incl self
        lp[li] = li;
    }
    __syncthreads();
    if (tid < 256) {   // flags -> global, 16B per thread
        int row = tid >> 2, chunk = tid & 3;
        ((uint4*)(flags + (size_t)(r0 + row) * WW + c0))[chunk] =
            ((const uint4*)lc8)[row * 4 + chunk];
    }
    // union dedup (8-conn): W and N unconditional; NW iff !N && !W;
    // NE iff !N && !E (covering unions W-of-N / W-of-NE / N-of-E are done
    // unconditionally at the covering pixel; union-find is order-independent)
    for (int li = tid; li < TILE; li += LTHREADS) {
        if (!(lc8[li] & 2)) continue;
        int lr = li >> 6, lc = li & 63;
        bool w = (lc > 0) && (lc8[li - 1] & 2);
        if (w) l_union(lp, li, li - 1);
        if (lr > 0) {
            bool n = (lc8[li - 64] & 2) != 0;
            if (n) {
                l_union(lp, li, li - 64);
            } else {
                if (!w && lc > 0 && (lc8[li - 65] & 2)) l_union(lp, li, li - 65);
                if (lc < 63 && !(lc8[li + 1] & 2) && (lc8[li - 63] & 2))
                    l_union(lp, li, li - 63);
            }
        }
    }
    __syncthreads();
    for (int li = tid; li < TILE; li += LTHREADS) {
        if (!(lc8[li] & 2)) continue;
        int root = li, p;
        while ((p = lp[root]) != root) root = p;   // lp stable after barrier
        int gi = (r0 + (li >> 6)) * WW + c0 + (li & 63);
        int gr = (r0 + (root >> 6)) * WW + c0 + (root & 63);
        parent[gi] = gr;
    }
}

// union only tile-crossing edges (R11-identical)
__global__ __launch_bounds__(THREADS) void k_merge(const uint8_t* __restrict__ flags,
                                                   int* __restrict__ parent) {
    int tile_x = blockIdx.x & 31, tile_y = blockIdx.x >> 5;
    int r0 = tile_y << 6, c0 = tile_x << 6;
    int t = threadIdx.x;
    int lane = t & 63;

    if (t < 64) {                                    // top row, lr=0, lc=t
        int r = r0, c = c0 + t, i = r * WW + c;
        bool selfC = (flags[i] & 2) != 0;
        bool nC = false, nwC = false, neC = false;
        if (selfC && r > 0) {
            nC  = (flags[i - WW] & 2) != 0;
            nwC = (c > 0)      && (flags[i - WW - 1] & 2);
            neC = (c < WW - 1) && (flags[i - WW + 1] & 2);
        }
        int did = 0, ra = -1, rb = -1;
        if (selfC && r > 0 && nC) { ra = uf_find(parent, i); rb = uf_find(parent, i - WW); did = 1; }
        int pra = __shfl_up(ra, 1), prb = __shfl_up(rb, 1), pdid = __shfl_up(did, 1);
        bool head = (lane == 0) || !pdid || pra != ra || prb != rb;
        if (did && head) uf_union(parent, ra, rb);
        if (selfC && r > 0) {
            if (t == 0) {
                if (nwC) uf_union(parent, i, i - WW - 1);          // diag tile
                if (!nC && neC) uf_union(parent, i, i - WW + 1);
            } else if (t == 63) {
                if (!nC && nwC) uf_union(parent, i, i - WW - 1);
                if (neC) {
                    bool eC = (c < WW - 1) && (flags[i + 1] & 2);
                    if (!eC) uf_union(parent, i, i - WW + 1);
                }
            } else if (!nC) {
                if (nwC) uf_union(parent, i, i - WW - 1);
                if (neC) uf_union(parent, i, i - WW + 1);
            }
        }
        if (t == 0 && selfC && c > 0 && (flags[i - 1] & 2))        // corner W edge
            uf_union(parent, i, i - 1);
    } else if (t < 127) {                            // left col, lr=1..63, lc=0
        int lr = t - 63;
        int r = r0 + lr, c = c0, i = r * WW + c;
        bool selfC = (flags[i] & 2) != 0;
        bool wC = false, nwC = false;
        if (selfC && c > 0) {
            wC  = (flags[i - 1] & 2) != 0;
            nwC = (flags[i - WW - 1] & 2) != 0;
        }
        int did = 0, ra = -1, rb = -1;
        if (selfC && wC) { ra = uf_find(parent, i); rb = uf_find(parent, i - 1); did = 1; }
        int pra = __shfl_up(ra, 1), prb = __shfl_up(rb, 1), pdid = __shfl_up(did, 1);
        bool head = (lane == 0) || !pdid || pra != ra || prb != rb;
        if (did && head) uf_union(parent, ra, rb);
        if (selfC && !wC && nwC) uf_union(parent, i, i - WW - 1);
    } else if (t < 190) {                            // right col, lr=1..63, lc=63
        int lr = t - 126;
        int r = r0 + lr, c = c0 + 63, i = r * WW + c;
        bool selfC = (flags[i] & 2) != 0;
        if (selfC && c < WW - 1) {
            bool neC = (flags[i - WW + 1] & 2) != 0;
            bool eC  = (flags[i + 1] & 2) != 0;
            if (neC && !eC) uf_union(parent, i, i - WW + 1);
        }
    }
}

// ---------------- border + stats with parent-value dedupe ----------------
__device__ __forceinline__ void h_insert(int* h_key, int p) {
    unsigned slot = (((unsigned)p * 2654435761u) >> 20) & (HSZ - 1);
    for (;;) {
        int old = atomicCAS(&h_key[slot], -1, p);
        if (old == -1 || old == p) return;
        slot = (slot + 1) & (HSZ - 1);
    }
}
__device__ __forceinline__ int h_lookup(const int* h_key, const int* h_root, int p) {
    unsigned slot = (((unsigned)p * 2654435761u) >> 20) & (HSZ - 1);
    for (;;) {
        if (h_key[slot] == p) return h_root[slot];
        slot = (slot + 1) & (HSZ - 1);
    }
}

__global__ __launch_bounds__(THREADS) void k_border_stats(
        const uint8_t* __restrict__ flags, int* __restrict__ parent,
        int* __restrict__ sizes, unsigned long long* __restrict__ colsum,
        int* __restrict__ cand, int* __restrict__ counter) {
    __shared__ int h_key[HSZ];
    __shared__ int h_root[HSZ];
    __shared__ int s_lab[HSZ];
    __shared__ int s_sz[HSZ];
    __shared__ u64 s_cs[HSZ];
    for (int t = threadIdx.x; t < HSZ; t += THREADS) {
        h_key[t] = -1; s_lab[t] = -1; s_sz[t] = 0; s_cs[t] = 0;
    }
    __syncthreads();

    const int i = blockIdx.x * THREADS + threadIdx.x;
    const int f = flags[i];
    const int r = i >> 11, c = i & (WW - 1);

    int pself = -1;
    int pnb[8];
    #pragma unroll
    for (int t = 0; t < 8; ++t) pnb[t] = -1;

    if (f & 2) {
        pself = parent[i];                       // coalesced
        h_insert(h_key, pself);
    } else if (f & 1) {                          // active non-core
        const int dr8[8] = {-1,-1,-1, 0,0, 1,1,1};
        const int dc8[8] = {-1, 0, 1,-1,1,-1,0,1};
        #pragma unroll
        for (int t = 0; t < 8; ++t) {
            int rr = r + dr8[t], cc = c + dc8[t];
            if ((unsigned)rr < HH && (unsigned)cc < WW) {
                int n = rr * WW + cc;
                if (flags[n] & 2) {
                    int p = parent[n];
                    pnb[t] = p;
                    h_insert(h_key, p);
                }
            }
        }
    }
    __syncthreads();
    // resolve each distinct parent value once
    for (int t = threadIdx.x; t < HSZ; t += THREADS) {
        int k = h_key[t];
        if (k >= 0) h_root[t] = uf_find(parent, k);
    }
    __syncthreads();

    int lab = BIGL;
    if (f & 2) {
        lab = h_lookup(h_key, h_root, pself);
    } else if (f & 1) {
        int m = BIGL;
        #pragma unroll
        for (int t = 0; t < 8; ++t)
            if (pnb[t] >= 0) { int v = h_lookup(h_key, h_root, pnb[t]); if (v < m) m = v; }
        lab = m;                     // BIGL if no core neighbor
    }

    // wave-level run aggregation (WW % 64 == 0: wave never crosses a row)
    int lane = threadIdx.x & 63;
    int labp = __shfl_up(lab, 1);
    bool head = (lane == 0) || (labp != lab);
    unsigned long long hm = __ballot(head);
    if (head && lab < BIGL) {
        unsigned long long rest = (hm >> lane) >> 1;
        int len = rest ? __ffsll((unsigned long long)rest) : (64 - lane);
        long long cc0 = (long long)(i & (WW - 1));
        u64 csum = (u64)(cc0 * len + (long long)len * (len - 1) / 2);
        unsigned slot = (((unsigned)lab * 2654435761u) >> 20) & (HSZ - 1);
        for (;;) {
            int old = atomicCAS(&s_lab[slot], -1, lab);
            if (old == -1 || old == lab) {
                atomicAdd(&s_sz[slot], len);
                atomicAdd(&s_cs[slot], csum);
                break;
            }
            slot = (slot + 1) & (HSZ - 1);
        }
    }
    __syncthreads();
    for (int t = threadIdx.x; t < HSZ; t += THREADS) {
        int lb = s_lab[t];
        if (lb >= 0) {
            int add = s_sz[t];
            int old = atomicAdd(&sizes[lb], add);
            if (old < MINCL && old + add >= MINCL) {   // exactly one block sees this
                int p = atomicAdd(counter, 1);
                cand[p] = lb;
            }
            atomicAdd(&colsum[lb], s_cs[t]);
        }
    }
}

// ---- fused single-kernel top-26 selection (R11-identical) ----
__device__ __forceinline__ u64 wave_min_u64(u64 m) {
    #pragma unroll
    for (int off = 32; off; off >>= 1) {
        u64 o = __shfl_xor(m, off);
        if (o < m) m = o;
    }
    return m;
}

__global__ __launch_bounds__(THREADS) void k_sel(const int* __restrict__ cand,
                                                 int* __restrict__ counter,   // [0]=n, [1]=done
                                                 const int* __restrict__ sizes,
                                                 const unsigned long long* __restrict__ colsum,
                                                 unsigned long long* __restrict__ top26g,
                                                 signed char* __restrict__ chan) {
    __shared__ u64 wout[4 * NSLOTS];
    const int tid = threadIdx.x, lane = tid & 63, wv = tid >> 6;
    const int n = counter[0];
    int slice = (n + NB - 1) / NB;
    int j0 = blockIdx.x * slice;
    int j1 = j0 + slice; if (j1 > n) j1 = n;
    int len = j1 - j0; if (len < 0) len = 0;
    int chunk = (len + 3) >> 2;
    int s0 = j0 + wv * chunk;
    int s1 = s0 + chunk; if (s1 > j1) s1 = j1;

    u64 kk[3] = { ~0ull, ~0ull, ~0ull };
    #pragma unroll
    for (int t = 0; t < 3; ++t) {
        int j = s0 + lane + 64 * t;
        if (j < s1) {
            int lab = cand[j];
            float mean = (float)colsum[lab] / (float)sizes[lab];
            kk[t] = ((u64)__float_as_uint(mean) << 32) | (unsigned)lab;
        }
    }
    for (int k = 0; k < NSLOTS; ++k) {
        u64 m = kk[0]; int li = 0;
        if (kk[1] < m) { m = kk[1]; li = 1; }
        if (kk[2] < m) { m = kk[2]; li = 2; }
        u64 mpre = m;
        m = wave_min_u64(m);
        if (mpre == m && m != ~0ull) kk[li] = ~0ull;
        if (lane == 0) wout[wv * NSLOTS + k] = m;
    }
    __syncthreads();
    if (wv == 0) {
        u64 a = (lane < 4 * NSLOTS) ? wout[lane] : ~0ull;
        u64 b = (lane + 64 < 4 * NSLOTS) ? wout[lane + 64] : ~0ull;
        for (int k = 0; k < NSLOTS; ++k) {
            u64 m = a < b ? a : b; int li = a < b ? 0 : 1;
            u64 mpre = m;
            m = wave_min_u64(m);
            if (mpre == m && m != ~0ull) { if (li == 0) a = ~0ull; else b = ~0ull; }
            if (lane == 0) top26g[blockIdx.x * NSLOTS + k] = m;
        }
    }
    __syncthreads();
    __shared__ int lastflag;
    if (tid == 0) {
        __threadfence();
        lastflag = (atomicAdd(&counter[1], 1) == NB - 1);
    }
    __syncthreads();
    if (!lastflag) return;

    u64 mk[13];
    #pragma unroll
    for (int t = 0; t < 13; ++t) {
        int j = wv * 832 + lane + 64 * t;
        mk[t] = __hip_atomic_load(&top26g[j], __ATOMIC_RELAXED, __HIP_MEMORY_SCOPE_AGENT);
    }
    for (int k = 0; k < NSLOTS; ++k) {
        u64 m = mk[0]; int li = 0;
        #pragma unroll
        for (int t = 1; t < 13; ++t) if (mk[t] < m) { m = mk[t]; li = t; }
        u64 mpre = m;
        m = wave_min_u64(m);
        if (mpre == m && m != ~0ull) mk[li] = ~0ull;
        if (lane == 0) wout[wv * NSLOTS + k] = m;
    }
    __syncthreads();
    if (wv == 0) {
        u64 a = (lane < 4 * NSLOTS) ? wout[lane] : ~0ull;
        u64 b = (lane + 64 < 4 * NSLOTS) ? wout[lane + 64] : ~0ull;
        for (int k = 0; k < NSLOTS; ++k) {
            u64 m = a < b ? a : b; int li = a < b ? 0 : 1;
            u64 mpre = m;
            m = wave_min_u64(m);
            if (mpre == m && m != ~0ull) { if (li == 0) a = ~0ull; else b = ~0ull; }
            if (lane == 0 && m != ~0ull)
                chan[(unsigned int)(m & 0xFFFFFFFFull)] = (signed char)k;
        }
    }
}

// ---------------- output: recompute labels (no labfull) + one-hot ----------------
__device__ __forceinline__ void h2_insert(int* hk, int p) {
    unsigned slot = (((unsigned)p * 2654435761u) >> 16) & (HSZ2 - 1);
    for (;;) {
        int old = atomicCAS(&hk[slot], -1, p);
        if (old == -1 || old == p) return;
        slot = (slot + 1) & (HSZ2 - 1);
    }
}
__device__ __forceinline__ int h2_lookup(const int* hk, const int* hr, int p) {
    unsigned slot = (((unsigned)p * 2654435761u) >> 16) & (HSZ2 - 1);
    for (;;) {
        if (hk[slot] == p) return hr[slot];
        slot = (slot + 1) & (HSZ2 - 1);
    }
}

__global__ __launch_bounds__(THREADS) void k_output(const uint8_t* __restrict__ flags,
                                                    int* __restrict__ parent,
                                                    const signed char* __restrict__ chan,
                                                    int* __restrict__ out) {
    __shared__ int hk[HSZ2];
    __shared__ int hr[HSZ2];
    for (int t = threadIdx.x; t < HSZ2; t += THREADS) hk[t] = -1;
    __syncthreads();
    const int i4 = (blockIdx.x * THREADS + threadIdx.x) * 4;
    uchar4 f4 = *(const uchar4*)(flags + i4);
    vi4 p4 = *(const vi4*)(parent + i4);
    const uint8_t ff[4] = { f4.x, f4.y, f4.z, f4.w };
    const int pv[4] = { p4.x, p4.y, p4.z, p4.w };
    int pnb[4][8];
    const int dr8[8] = {-1,-1,-1, 0,0, 1,1,1};
    const int dc8[8] = {-1, 0, 1,-1,1,-1,0,1};
    #pragma unroll
    for (int t = 0; t < 4; ++t) {
        #pragma unroll
        for (int e = 0; e < 8; ++e) pnb[t][e] = -1;
        int f = ff[t];
        if (f & 2) {
            h2_insert(hk, pv[t]);
        } else if (f & 1) {
            int i = i4 + t;
            int r = i >> 11, c = i & (WW - 1);
            #pragma unroll
            for (int e = 0; e < 8; ++e) {
                int rr = r + dr8[e], cc = c + dc8[e];
                if ((unsigned)rr < HH && (unsigned)cc < WW) {
                    int n = rr * WW + cc;
                    if (flags[n] & 2) { int p = parent[n]; pnb[t][e] = p; h2_insert(hk, p); }
                }
            }
        }
    }
    __syncthreads();
    for (int t = threadIdx.x; t < HSZ2; t += THREADS) {
        int k = hk[t];
        if (k >= 0) hr[t] = uf_find(parent, k);    // ~1 hop: paths halved by stats
    }
    __syncthreads();
    int chv[4];
    #pragma unroll
    for (int t = 0; t < 4; ++t) {
        int f = ff[t];
        int lab = BIGL;
        if (f & 2) {
            lab = h2_lookup(hk, hr, pv[t]);
        } else if (f & 1) {
            int m = BIGL;
            #pragma unroll
            for (int e = 0; e < 8; ++e)
                if (pnb[t][e] >= 0) { int v = h2_lookup(hk, hr, pnb[t][e]); if (v < m) m = v; }
            lab = m;
        }
        chv[t] = (lab < BIGL) ? (int)chan[lab] : -1;
    }
    #pragma unroll
    for (int c = 0; c < NSLOTS; ++c) {
        vi4 v;
        v.x = (chv[0] == c) ? 1 : 0;
        v.y = (chv[1] == c) ? 1 : 0;
        v.z = (chv[2] == c) ? 1 : 0;
        v.w = (chv[3] == c) ? 1 : 0;
        __builtin_nontemporal_store(v, (vi4*)(out + (size_t)c * HWN + i4));
    }
}

extern "C" void kernel_launch(void* const* d_in, const int* in_sizes, int n_in,
                              void* d_out, int out_size, void* d_ws, size_t ws_size,
                              hipStream_t stream) {
    const float* mask = (const float*)d_in[0];
    int* out = (int*)d_out;

    char* w = (char*)d_ws;
    int* parent                 = (int*)(w);                          //  8 MB
    int* sizes                  = (int*)(w + (size_t)HWN * 8);        //  8 MB
    unsigned long long* colsum  = (unsigned long long*)(w + (size_t)HWN * 12); // 16 MB
    uint8_t* flags              = (uint8_t*)(w + (size_t)HWN * 20);   //  2 MB
    signed char* chan           = (signed char*)(w + (size_t)HWN * 21); // 2 MB
    int* cand                   = (int*)(w + (size_t)HWN * 22);       // 280 KB
    int* counter                = (int*)(w + (size_t)HWN * 22 + MAXCAND * 4);  // [0]=n,[1]=done
    unsigned long long* top26g  = (unsigned long long*)(w + (size_t)HWN * 22 + MAXCAND * 4 + 256);

    // no memsets: k_local zeros sizes/colsum/chan/counter/done
    const int blocks = HWN / THREADS;   // 8192
    k_local       <<<NTILES, LTHREADS, 0, stream>>>(mask, flags, parent,
                                                    sizes, colsum, chan, counter);
    k_merge       <<<NTILES, THREADS, 0, stream>>>(flags, parent);
    k_border_stats<<<blocks, THREADS, 0, stream>>>(flags, parent, sizes, colsum,
                                                   cand, counter);
    k_sel         <<<NB, THREADS, 0, stream>>>(cand, counter, sizes, colsum, top26g, chan);
    k_output      <<<HWN / (4 * THREADS), THREADS, 0, stream>>>(flags, parent, chan, out);
}

// Round 13
// 392.736 us; speedup vs baseline: 1.0347x; 1.0347x over previous
//
#include <hip/hip_runtime.h>
#include <stdint.h>

#define HH 1024
#define WW 2048
#define HWN (HH*WW)          // 2097152
#define BIGL HWN             // 'no cluster' sentinel
#define NSLOTS 26
#define MINCL 30
#define THREADS 256
#define LTHREADS 512         // k_local block size (8 waves)
#define MAXCAND 70000        // >= HWN/30 + 1
#define HK 1024              // border_stats hash entries (512-pixel strip)
#define TILE 4096            // 64x64 tile
#define NTILES 512           // (1024/64)*(2048/64)
#define NB 128               // selection blocks
#define SBLK 4096            // border_stats blocks (2 px/thread)

typedef int vi4 __attribute__((ext_vector_type(4)));
typedef unsigned long long u64;

// ---------------- global union-find (lock-free, min-root) ----------------
__device__ __forceinline__ int uf_load(int* p, int i) {
    return __hip_atomic_load(&p[i], __ATOMIC_RELAXED, __HIP_MEMORY_SCOPE_AGENT);
}
__device__ __forceinline__ void uf_store(int* p, int i, int v) {
    __hip_atomic_store(&p[i], v, __ATOMIC_RELAXED, __HIP_MEMORY_SCOPE_AGENT);
}
__device__ int uf_find(int* parent, int x) {
    int p = uf_load(parent, x);
    while (p != x) {
        int gp = uf_load(parent, p);
        if (gp != p) uf_store(parent, x, gp);   // path halving (benign race)
        x = p; p = gp;
    }
    return p;
}
__device__ void uf_union(int* parent, int a, int b) {
    int ra = uf_find(parent, a);
    int rb = uf_find(parent, b);
    while (ra != rb) {
        if (ra > rb) { int t = ra; ra = rb; rb = t; }   // hook larger under smaller
        int old = atomicCAS(&parent[rb], rb, ra);
        if (old == rb) return;
        rb = uf_find(parent, old);
        ra = uf_find(parent, ra);
    }
}

// ---------------- LDS union-find (block-local, min-root) ----------------
__device__ __forceinline__ int l_load(int* p, int i) {
    return __hip_atomic_load(&p[i], __ATOMIC_RELAXED, __HIP_MEMORY_SCOPE_WORKGROUP);
}
__device__ __forceinline__ void l_store(int* p, int i, int v) {
    __hip_atomic_store(&p[i], v, __ATOMIC_RELAXED, __HIP_MEMORY_SCOPE_WORKGROUP);
}
__device__ int l_find(int* lp, int x) {
    int p = l_load(lp, x);
    while (p != x) {
        int gp = l_load(lp, p);
        if (gp != p) l_store(lp, x, gp);
        x = p; p = gp;
    }
    return p;
}
__device__ void l_union(int* lp, int a, int b) {
    int ra = l_find(lp, a);
    int rb = l_find(lp, b);
    while (ra != rb) {
        if (ra > rb) { int t = ra; ra = rb; rb = t; }
        int old = atomicCAS(&lp[rb], rb, ra);
        if (old == rb) return;
        rb = l_find(lp, old);
        ra = l_find(lp, ra);
    }
}

// ---------------- fused init + per-tile CC + ws zeroing (R11-identical) ----------------
__global__ __launch_bounds__(LTHREADS) void k_local(const float* __restrict__ mask,
                                                    uint8_t* __restrict__ flags,
                                                    int* __restrict__ parent,
                                                    int* __restrict__ sizes,
                                                    unsigned long long* __restrict__ colsum,
                                                    signed char* __restrict__ chan,
                                                    int* __restrict__ counter) {
    __shared__ uint8_t lact[66 * 72];   // halo active map, row stride 72
    __shared__ uint8_t lc8[TILE];
    __shared__ int lp[TILE];
    const int tid = threadIdx.x;
    int tile_x = blockIdx.x & 31, tile_y = blockIdx.x >> 5;
    int r0 = tile_y << 6, c0 = tile_x << 6;

    {   // zero this block's 1/512 slice of sizes/colsum/chan (+counter/done once)
        int base = blockIdx.x * (HWN / NTILES);      // 4096 elements
        vi4* sz4 = (vi4*)(sizes + base);
        vi4* cs4 = (vi4*)(colsum + base);
        for (int t = tid; t < 1024; t += LTHREADS) sz4[t] = (vi4)0;
        for (int t = tid; t < 2048; t += LTHREADS) cs4[t] = (vi4)0;
        vi4* ch4 = (vi4*)(chan + base);
        for (int t = tid; t < 256; t += LTHREADS) ch4[t] = (vi4)(-1);
        if (blockIdx.x == 0 && tid == 0) { counter[0] = 0; counter[1] = 0; }
    }

    {   // body rows: 64 rows x 16 float4, coalesced; 512 threads -> 2 passes
        int lr = tid >> 4, q = tid & 15;
        #pragma unroll
        for (int pass = 0; pass < 2; ++pass) {
            int rr = lr + pass * 32;
            const float4* src = (const float4*)(mask + (size_t)(r0 + rr) * WW + c0);
            float4 v = src[q];
            uint8_t* dst = &lact[(rr + 1) * 72 + (q * 4 + 1)];
            dst[0] = v.x > 0.1f; dst[1] = v.y > 0.1f;
            dst[2] = v.z > 0.1f; dst[3] = v.w > 0.1f;
        }
    }
    if (tid < 32) {          // halo top/bottom rows (cols 1..64)
        int q = tid & 15;
        bool top = tid < 16;
        int gr = top ? r0 - 1 : r0 + 64;
        int yy = top ? 0 : 65;
        uint8_t* dst = &lact[yy * 72 + (q * 4 + 1)];
        if ((unsigned)gr < HH) {
            const float4* src = (const float4*)(mask + (size_t)gr * WW + c0);
            float4 v = src[q];
            dst[0] = v.x > 0.1f; dst[1] = v.y > 0.1f;
            dst[2] = v.z > 0.1f; dst[3] = v.w > 0.1f;
        } else {
            dst[0] = 0; dst[1] = 0; dst[2] = 0; dst[3] = 0;
        }
    } else if (tid >= 64 && tid < 64 + 132) {   // halo cols incl corners
        int lane = tid - 64;                    // 0..131
        int side = lane >= 66;                  // 0=left(c0-1), 1=right(c0+64)
        int yy = side ? lane - 66 : lane;       // 0..65
        int gr = r0 - 1 + yy;
        int gc = side ? c0 + 64 : c0 - 1;
        bool a = false;
        if ((unsigned)gr < HH && (unsigned)gc < WW) a = mask[(size_t)gr * WW + gc] > 0.1f;
        lact[yy * 72 + (side ? 65 : 0)] = a ? 1 : 0;
    }
    __syncthreads();
    for (int li = tid; li < TILE; li += LTHREADS) {
        int lr = li >> 6, lc = li & 63;
        int b = (lr + 1) * 72 + (lc + 1);
        int a = lact[b];
        int cnt = lact[b - 73] + lact[b - 72] + lact[b - 71]
                + lact[b - 1]  + a           + lact[b + 1]
                + lact[b + 71] + lact[b + 72] + lact[b + 73];
        lc8[li] = (uint8_t)(a | ((a && cnt >= 4) ? 2 : 0));  // MIN_SAMPLES=4 incl self
        lp[li] = li;
    }
    __syncthreads();
    if (tid < 256) {   // flags -> global, 16B per thread
        int row = tid >> 2, chunk = tid & 3;
        ((uint4*)(flags + (size_t)(r0 + row) * WW + c0))[chunk] =
            ((const uint4*)lc8)[row * 4 + chunk];
    }
    for (int li = tid; li < TILE; li += LTHREADS) {
        if (!(lc8[li] & 2)) continue;
        int lr = li >> 6, lc = li & 63;
        if (lc > 0 && (lc8[li - 1] & 2)) l_union(lp, li, li - 1);
        if (lr > 0) {
            if (lc > 0  && (lc8[li - 65] & 2)) l_union(lp, li, li - 65);
            if (           (lc8[li - 64] & 2)) l_union(lp, li, li - 64);
            if (lc < 63 && (lc8[li - 63] & 2)) l_union(lp, li, li - 63);
        }
    }
    __syncthreads();
    for (int li = tid; li < TILE; li += LTHREADS) {
        if (!(lc8[li] & 2)) continue;
        int root = li, p;
        while ((p = lp[root]) != root) root = p;   // lp stable after barrier
        int gi = (r0 + (li >> 6)) * WW + c0 + (li & 63);
        int gr = (r0 + (root >> 6)) * WW + c0 + (root & 63);
        parent[gi] = gr;
    }
}

// union only tile-crossing edges (R11-identical)
__global__ __launch_bounds__(THREADS) void k_merge(const uint8_t* __restrict__ flags,
                                                   int* __restrict__ parent) {
    int tile_x = blockIdx.x & 31, tile_y = blockIdx.x >> 5;
    int r0 = tile_y << 6, c0 = tile_x << 6;
    int t = threadIdx.x;
    int lane = t & 63;

    if (t < 64) {                                    // top row, lr=0, lc=t
        int r = r0, c = c0 + t, i = r * WW + c;
        bool selfC = (flags[i] & 2) != 0;
        bool nC = false, nwC = false, neC = false;
        if (selfC && r > 0) {
            nC  = (flags[i - WW] & 2) != 0;
            nwC = (c > 0)      && (flags[i - WW - 1] & 2);
            neC = (c < WW - 1) && (flags[i - WW + 1] & 2);
        }
        int did = 0, ra = -1, rb = -1;
        if (selfC && r > 0 && nC) { ra = uf_find(parent, i); rb = uf_find(parent, i - WW); did = 1; }
        int pra = __shfl_up(ra, 1), prb = __shfl_up(rb, 1), pdid = __shfl_up(did, 1);
        bool head = (lane == 0) || !pdid || pra != ra || prb != rb;
        if (did && head) uf_union(parent, ra, rb);
        if (selfC && r > 0) {
            if (t == 0) {
                if (nwC) uf_union(parent, i, i - WW - 1);          // diag tile
                if (!nC && neC) uf_union(parent, i, i - WW + 1);
            } else if (t == 63) {
                if (!nC && nwC) uf_union(parent, i, i - WW - 1);
                if (neC) {
                    bool eC = (c < WW - 1) && (flags[i + 1] & 2);
                    if (!eC) uf_union(parent, i, i - WW + 1);
                }
            } else if (!nC) {
                if (nwC) uf_union(parent, i, i - WW - 1);
                if (neC) uf_union(parent, i, i - WW + 1);
            }
        }
        if (t == 0 && selfC && c > 0 && (flags[i - 1] & 2))        // corner W edge
            uf_union(parent, i, i - 1);
    } else if (t < 127) {                            // left col, lr=1..63, lc=0
        int lr = t - 63;
        int r = r0 + lr, c = c0, i = r * WW + c;
        bool selfC = (flags[i] & 2) != 0;
        bool wC = false, nwC = false;
        if (selfC && c > 0) {
            wC  = (flags[i - 1] & 2) != 0;
            nwC = (flags[i - WW - 1] & 2) != 0;
        }
        int did = 0, ra = -1, rb = -1;
        if (selfC && wC) { ra = uf_find(parent, i); rb = uf_find(parent, i - 1); did = 1; }
        int pra = __shfl_up(ra, 1), prb = __shfl_up(rb, 1), pdid = __shfl_up(did, 1);
        bool head = (lane == 0) || !pdid || pra != ra || prb != rb;
        if (did && head) uf_union(parent, ra, rb);
        if (selfC && !wC && nwC) uf_union(parent, i, i - WW - 1);
    } else if (t < 190) {                            // right col, lr=1..63, lc=63
        int lr = t - 126;
        int r = r0 + lr, c = c0 + 63, i = r * WW + c;
        bool selfC = (flags[i] & 2) != 0;
        if (selfC && c < WW - 1) {
            bool neC = (flags[i - WW + 1] & 2) != 0;
            bool eC  = (flags[i + 1] & 2) != 0;
            if (neC && !eC) uf_union(parent, i, i - WW + 1);
        }
    }
}

// ---------------- border + stats, 2 px/thread, parent-value dedupe ----------------
__device__ __forceinline__ void h_insert(int* h_key, int p) {
    unsigned slot = (((unsigned)p * 2654435761u) >> 18) & (HK - 1);
    for (;;) {
        int old = atomicCAS(&h_key[slot], -1, p);
        if (old == -1 || old == p) return;
        slot = (slot + 1) & (HK - 1);
    }
}
__device__ __forceinline__ int h_lookup(const int* h_key, const int* h_root, int p) {
    unsigned slot = (((unsigned)p * 2654435761u) >> 18) & (HK - 1);
    for (;;) {
        if (h_key[slot] == p) return h_root[slot];
        slot = (slot + 1) & (HK - 1);
    }
}
__device__ __forceinline__ void s_add(int* s_lab, int* s_sz, u64* s_cs,
                                      int lab, int len, u64 csum) {
    unsigned slot = (((unsigned)lab * 2654435761u) >> 18) & (HK - 1);
    for (;;) {
        int old = atomicCAS(&s_lab[slot], -1, lab);
        if (old == -1 || old == lab) {
            atomicAdd(&s_sz[slot], len);
            atomicAdd(&s_cs[slot], csum);
            return;
        }
        slot = (slot + 1) & (HK - 1);
    }
}

__global__ __launch_bounds__(THREADS) void k_border_stats(
        const uint8_t* __restrict__ flags, int* __restrict__ parent,
        int* __restrict__ labfull, int* __restrict__ sizes,
        unsigned long long* __restrict__ colsum,
        int* __restrict__ cand, int* __restrict__ counter) {
    __shared__ int h_key[HK];
    __shared__ int h_root[HK];
    __shared__ int s_lab[HK];
    __shared__ int s_sz[HK];
    __shared__ u64 s_cs[HK];
    for (int t = threadIdx.x; t < HK; t += THREADS) {
        h_key[t] = -1; s_lab[t] = -1; s_sz[t] = 0; s_cs[t] = 0;
    }
    __syncthreads();

    const int i2 = (blockIdx.x * THREADS + threadIdx.x) * 2;
    uchar2 f2 = *(const uchar2*)(flags + i2);
    int2 p2 = *(const int2*)(parent + i2);
    const uint8_t ff[2] = { f2.x, f2.y };
    const int pv[2] = { p2.x, p2.y };
    int pnb[2][8];
    const int dr8[8] = {-1,-1,-1, 0,0, 1,1,1};
    const int dc8[8] = {-1, 0, 1,-1,1,-1,0,1};
    #pragma unroll
    for (int t = 0; t < 2; ++t) {
        #pragma unroll
        for (int e = 0; e < 8; ++e) pnb[t][e] = -1;
        int f = ff[t];
        if (f & 2) {
            h_insert(h_key, pv[t]);
        } else if (f & 1) {                      // active non-core
            int i = i2 + t;
            int r = i >> 11, c = i & (WW - 1);
            #pragma unroll
            for (int e = 0; e < 8; ++e) {
                int rr = r + dr8[e], cc = c + dc8[e];
                if ((unsigned)rr < HH && (unsigned)cc < WW) {
                    int n = rr * WW + cc;
                    if (flags[n] & 2) { int p = parent[n]; pnb[t][e] = p; h_insert(h_key, p); }
                }
            }
        }
    }
    __syncthreads();
    for (int t = threadIdx.x; t < HK; t += THREADS) {   // one find per distinct value
        int k = h_key[t];
        if (k >= 0) h_root[t] = uf_find(parent, k);
    }
    __syncthreads();

    int lab[2];
    #pragma unroll
    for (int t = 0; t < 2; ++t) {
        int f = ff[t];
        lab[t] = BIGL;
        if (f & 2) {
            lab[t] = h_lookup(h_key, h_root, pv[t]);
        } else if (f & 1) {
            int m = BIGL;
            #pragma unroll
            for (int e = 0; e < 8; ++e)
                if (pnb[t][e] >= 0) { int v = h_lookup(h_key, h_root, pnb[t][e]); if (v < m) m = v; }
            lab[t] = m;
        }
    }
    *(int2*)(labfull + i2) = make_int2(lab[0], lab[1]);

    // run aggregation over thread pairs (wave covers 128 consecutive px, no row cross)
    const int lane = threadIdx.x & 63;
    const int ch = i2 & (WW - 1);                 // col of first pixel
    bool uni = (lab[0] == lab[1]);
    bool chainable = uni && lab[0] < BIGL;
    int prevLab = __shfl_up(lab[1], 1);
    int prevCh  = __shfl_up(chainable ? 1 : 0, 1);
    bool link = chainable && lane > 0 && prevCh && prevLab == lab[0];
    u64 B = __ballot(link);
    bool headT = chainable && !link;
    if (headT) {
        u64 rest = (B >> lane) >> 1;              // links of following lanes
        int k = rest ? (__ffsll((unsigned long long)~rest) - 1) : 0;  // consecutive 1s
        long long m = k + 1;                      // threads in this run
        // pixels: cols ch .. ch+2m-1  =>  sz = 2m, csum = 2m*ch + 2m^2 - m
        s_add(s_lab, s_sz, s_cs, lab[0], (int)(2 * m),
              (u64)(2 * m * (long long)ch + 2 * m * m - m));
    }
    if (!uni) {
        #pragma unroll
        for (int t = 0; t < 2; ++t)
            if (lab[t] < BIGL) s_add(s_lab, s_sz, s_cs, lab[t], 1, (u64)(ch + t));
    }
    __syncthreads();
    for (int t = threadIdx.x; t < HK; t += THREADS) {
        int lb = s_lab[t];
        if (lb >= 0) {
            int add = s_sz[t];
            int old = atomicAdd(&sizes[lb], add);
            if (old < MINCL && old + add >= MINCL) {   // exactly one block sees this
                int p = atomicAdd(counter, 1);
                cand[p] = lb;
            }
            atomicAdd(&colsum[lb], s_cs[t]);
        }
    }
}

// ---- fused single-kernel top-26 selection (R11-identical) ----
__device__ __forceinline__ u64 wave_min_u64(u64 m) {
    #pragma unroll
    for (int off = 32; off; off >>= 1) {
        u64 o = __shfl_xor(m, off);
        if (o < m) m = o;
    }
    return m;
}

__global__ __launch_bounds__(THREADS) void k_sel(const int* __restrict__ cand,
                                                 int* __restrict__ counter,   // [0]=n, [1]=done
                                                 const int* __restrict__ sizes,
                                                 const unsigned long long* __restrict__ colsum,
                                                 unsigned long long* __restrict__ top26g,
                                                 signed char* __restrict__ chan) {
    __shared__ u64 wout[4 * NSLOTS];
    const int tid = threadIdx.x, lane = tid & 63, wv = tid >> 6;
    const int n = counter[0];
    int slice = (n + NB - 1) / NB;
    int j0 = blockIdx.x * slice;
    int j1 = j0 + slice; if (j1 > n) j1 = n;
    int len = j1 - j0; if (len < 0) len = 0;
    int chunk = (len + 3) >> 2;
    int s0 = j0 + wv * chunk;
    int s1 = s0 + chunk; if (s1 > j1) s1 = j1;

    u64 kk[3] = { ~0ull, ~0ull, ~0ull };
    #pragma unroll
    for (int t = 0; t < 3; ++t) {
        int j = s0 + lane + 64 * t;
        if (j < s1) {
            int lab = cand[j];
            float mean = (float)colsum[lab] / (float)sizes[lab];
            kk[t] = ((u64)__float_as_uint(mean) << 32) | (unsigned)lab;
        }
    }
    for (int k = 0; k < NSLOTS; ++k) {
        u64 m = kk[0]; int li = 0;
        if (kk[1] < m) { m = kk[1]; li = 1; }
        if (kk[2] < m) { m = kk[2]; li = 2; }
        u64 mpre = m;
        m = wave_min_u64(m);
        if (mpre == m && m != ~0ull) kk[li] = ~0ull;
        if (lane == 0) wout[wv * NSLOTS + k] = m;
    }
    __syncthreads();
    if (wv == 0) {
        u64 a = (lane < 4 * NSLOTS) ? wout[lane] : ~0ull;
        u64 b = (lane + 64 < 4 * NSLOTS) ? wout[lane + 64] : ~0ull;
        for (int k = 0; k < NSLOTS; ++k) {
            u64 m = a < b ? a : b; int li = a < b ? 0 : 1;
            u64 mpre = m;
            m = wave_min_u64(m);
            if (mpre == m && m != ~0ull) { if (li == 0) a = ~0ull; else b = ~0ull; }
            if (lane == 0) top26g[blockIdx.x * NSLOTS + k] = m;
        }
    }
    __syncthreads();
    __shared__ int lastflag;
    if (tid == 0) {
        __threadfence();
        lastflag = (atomicAdd(&counter[1], 1) == NB - 1);
    }
    __syncthreads();
    if (!lastflag) return;

    u64 mk[13];
    #pragma unroll
    for (int t = 0; t < 13; ++t) {
        int j = wv * 832 + lane + 64 * t;
        mk[t] = __hip_atomic_load(&top26g[j], __ATOMIC_RELAXED, __HIP_MEMORY_SCOPE_AGENT);
    }
    for (int k = 0; k < NSLOTS; ++k) {
        u64 m = mk[0]; int li = 0;
        #pragma unroll
        for (int t = 1; t < 13; ++t) if (mk[t] < m) { m = mk[t]; li = t; }
        u64 mpre = m;
        m = wave_min_u64(m);
        if (mpre == m && m != ~0ull) mk[li] = ~0ull;
        if (lane == 0) wout[wv * NSLOTS + k] = m;
    }
    __syncthreads();
    if (wv == 0) {
        u64 a = (lane < 4 * NSLOTS) ? wout[lane] : ~0ull;
        u64 b = (lane + 64 < 4 * NSLOTS) ? wout[lane + 64] : ~0ull;
        for (int k = 0; k < NSLOTS; ++k) {
            u64 m = a < b ? a : b; int li = a < b ? 0 : 1;
            u64 mpre = m;
            m = wave_min_u64(m);
            if (mpre == m && m != ~0ull) { if (li == 0) a = ~0ull; else b = ~0ull; }
            if (lane == 0 && m != ~0ull)
                chan[(unsigned int)(m & 0xFFFFFFFFull)] = (signed char)k;
        }
    }
}

// one-hot 26xHxW int32 output, non-temporal int4 stores (R11-identical)
__global__ __launch_bounds__(THREADS) void k_output(const int* __restrict__ labfull,
                                                    const signed char* __restrict__ chan,
                                                    int* __restrict__ out) {
    int i4 = (blockIdx.x * THREADS + threadIdx.x) * 4;
    int chv[4];
    #pragma unroll
    for (int t = 0; t < 4; ++t) {
        int lab = labfull[i4 + t];
        chv[t] = (lab < BIGL) ? (int)chan[lab] : -1;
    }
    #pragma unroll
    for (int c = 0; c < NSLOTS; ++c) {
        vi4 v;
        v.x = (chv[0] == c) ? 1 : 0;
        v.y = (chv[1] == c) ? 1 : 0;
        v.z = (chv[2] == c) ? 1 : 0;
        v.w = (chv[3] == c) ? 1 : 0;
        __builtin_nontemporal_store(v, (vi4*)(out + (size_t)c * HWN + i4));
    }
}

extern "C" void kernel_launch(void* const* d_in, const int* in_sizes, int n_in,
                              void* d_out, int out_size, void* d_ws, size_t ws_size,
                              hipStream_t stream) {
    const float* mask = (const float*)d_in[0];
    int* out = (int*)d_out;

    char* w = (char*)d_ws;
    int* parent                 = (int*)(w);                          //  8 MB
    int* labfull                = (int*)(w + (size_t)HWN * 4);        //  8 MB
    int* sizes                  = (int*)(w + (size_t)HWN * 8);        //  8 MB
    unsigned long long* colsum  = (unsigned long long*)(w + (size_t)HWN * 12); // 16 MB
    uint8_t* flags              = (uint8_t*)(w + (size_t)HWN * 20);   //  2 MB
    signed char* chan           = (signed char*)(w + (size_t)HWN * 21); // 2 MB
    int* cand                   = (int*)(w + (size_t)HWN * 22);       // 280 KB
    int* counter                = (int*)(w + (size_t)HWN * 22 + MAXCAND * 4);  // [0]=n,[1]=done
    unsigned long long* top26g  = (unsigned long long*)(w + (size_t)HWN * 22 + MAXCAND * 4 + 256);

    // no memsets: k_local zeros sizes/colsum/chan/counter/done
    k_local       <<<NTILES, LTHREADS, 0, stream>>>(mask, flags, parent,
                                                    sizes, colsum, chan, counter);
    k_merge       <<<NTILES, THREADS, 0, stream>>>(flags, parent);
    k_border_stats<<<SBLK, THREADS, 0, stream>>>(flags, parent, labfull, sizes, colsum,
                                                 cand, counter);
    k_sel         <<<NB, THREADS, 0, stream>>>(cand, counter, sizes, colsum, top26g, chan);
    k_output      <<<HWN / (4 * THREADS), THREADS, 0, stream>>>(labfull, chan, out);
}

// Round 14
// 391.985 us; speedup vs baseline: 1.0367x; 1.0019x over previous
//
#include <hip/hip_runtime.h>
#include <stdint.h>

#define HH 1024
#define WW 2048
#define HWN (HH*WW)          // 2097152
#define BIGL HWN             // 'no cluster' sentinel
#define NSLOTS 26
#define MINCL 30
#define THREADS 256
#define LTHREADS 512         // k_local block size (8 waves)
#define MAXCAND 70000        // >= HWN/30 + 1
#define HSZ 512              // border_stats hash entries (256-pixel strip)
#define TILE 4096            // 64x64 tile
#define NTILES 512           // (1024/64)*(2048/64)
#define NB 128               // selection blocks

typedef int vi4 __attribute__((ext_vector_type(4)));
typedef unsigned long long u64;

// ---------------- global union-find (lock-free, min-root) ----------------
__device__ __forceinline__ int uf_load(int* p, int i) {
    return __hip_atomic_load(&p[i], __ATOMIC_RELAXED, __HIP_MEMORY_SCOPE_AGENT);
}
__device__ __forceinline__ void uf_store(int* p, int i, int v) {
    __hip_atomic_store(&p[i], v, __ATOMIC_RELAXED, __HIP_MEMORY_SCOPE_AGENT);
}
__device__ int uf_find(int* parent, int x) {
    int p = uf_load(parent, x);
    while (p != x) {
        int gp = uf_load(parent, p);
        if (gp != p) uf_store(parent, x, gp);   // path halving (benign race)
        x = p; p = gp;
    }
    return p;
}
__device__ void uf_union(int* parent, int a, int b) {
    int ra = uf_find(parent, a);
    int rb = uf_find(parent, b);
    while (ra != rb) {
        if (ra > rb) { int t = ra; ra = rb; rb = t; }   // hook larger under smaller
        int old = atomicCAS(&parent[rb], rb, ra);
        if (old == rb) return;
        rb = uf_find(parent, old);
        ra = uf_find(parent, ra);
    }
}

// ---------------- LDS union-find (block-local, min-root) ----------------
__device__ __forceinline__ int l_load(int* p, int i) {
    return __hip_atomic_load(&p[i], __ATOMIC_RELAXED, __HIP_MEMORY_SCOPE_WORKGROUP);
}
__device__ __forceinline__ void l_store(int* p, int i, int v) {
    __hip_atomic_store(&p[i], v, __ATOMIC_RELAXED, __HIP_MEMORY_SCOPE_WORKGROUP);
}
__device__ int l_find(int* lp, int x) {
    int p = l_load(lp, x);
    while (p != x) {
        int gp = l_load(lp, p);
        if (gp != p) l_store(lp, x, gp);
        x = p; p = gp;
    }
    return p;
}
__device__ void l_union(int* lp, int a, int b) {
    int ra = l_find(lp, a);
    int rb = l_find(lp, b);
    while (ra != rb) {
        if (ra > rb) { int t = ra; ra = rb; rb = t; }
        int old = atomicCAS(&lp[rb], rb, ra);
        if (old == rb) return;
        rb = l_find(lp, old);
        ra = l_find(lp, ra);
    }
}

// ---------------- fused init + per-tile CC + ws zeroing ----------------
__global__ __launch_bounds__(LTHREADS) void k_local(const float* __restrict__ mask,
                                                    uint8_t* __restrict__ flags,
                                                    int* __restrict__ parent,
                                                    int* __restrict__ sizes,
                                                    unsigned long long* __restrict__ colsum,
                                                    signed char* __restrict__ chan,
                                                    int* __restrict__ counter) {
    __shared__ uint8_t lact[66 * 72];   // halo active map, row stride 72
    __shared__ uint8_t lc8[TILE];
    __shared__ int lp[TILE];
    const int tid = threadIdx.x;
    int tile_x = blockIdx.x & 31, tile_y = blockIdx.x >> 5;
    int r0 = tile_y << 6, c0 = tile_x << 6;

    {   // zero this block's 1/512 slice of sizes/colsum/chan (+counter/done once)
        int base = blockIdx.x * (HWN / NTILES);      // 4096 elements
        vi4* sz4 = (vi4*)(sizes + base);
        vi4* cs4 = (vi4*)(colsum + base);
        for (int t = tid; t < 1024; t += LTHREADS) sz4[t] = (vi4)0;
        for (int t = tid; t < 2048; t += LTHREADS) cs4[t] = (vi4)0;
        vi4* ch4 = (vi4*)(chan + base);
        for (int t = tid; t < 256; t += LTHREADS) ch4[t] = (vi4)(-1);
        if (blockIdx.x == 0 && tid == 0) { counter[0] = 0; counter[1] = 0; }
    }

    {   // body rows: 64 rows x 16 float4, coalesced; 512 threads -> 2 passes
        int lr = tid >> 4, q = tid & 15;
        #pragma unroll
        for (int pass = 0; pass < 2; ++pass) {
            int rr = lr + pass * 32;
            const float4* src = (const float4*)(mask + (size_t)(r0 + rr) * WW + c0);
            float4 v = src[q];
            uint8_t* dst = &lact[(rr + 1) * 72 + (q * 4 + 1)];
            dst[0] = v.x > 0.1f; dst[1] = v.y > 0.1f;
            dst[2] = v.z > 0.1f; dst[3] = v.w > 0.1f;
        }
    }
    if (tid < 32) {          // halo top/bottom rows (cols 1..64)
        int q = tid & 15;
        bool top = tid < 16;
        int gr = top ? r0 - 1 : r0 + 64;
        int yy = top ? 0 : 65;
        uint8_t* dst = &lact[yy * 72 + (q * 4 + 1)];
        if ((unsigned)gr < HH) {
            const float4* src = (const float4*)(mask + (size_t)gr * WW + c0);
            float4 v = src[q];
            dst[0] = v.x > 0.1f; dst[1] = v.y > 0.1f;
            dst[2] = v.z > 0.1f; dst[3] = v.w > 0.1f;
        } else {
            dst[0] = 0; dst[1] = 0; dst[2] = 0; dst[3] = 0;
        }
    } else if (tid >= 64 && tid < 64 + 132) {   // halo cols incl corners
        int lane = tid - 64;                    // 0..131
        int side = lane >= 66;                  // 0=left(c0-1), 1=right(c0+64)
        int yy = side ? lane - 66 : lane;       // 0..65
        int gr = r0 - 1 + yy;
        int gc = side ? c0 + 64 : c0 - 1;
        bool a = false;
        if ((unsigned)gr < HH && (unsigned)gc < WW) a = mask[(size_t)gr * WW + gc] > 0.1f;
        lact[yy * 72 + (side ? 65 : 0)] = a ? 1 : 0;
    }
    __syncthreads();
    for (int li = tid; li < TILE; li += LTHREADS) {
        int lr = li >> 6, lc = li & 63;
        int b = (lr + 1) * 72 + (lc + 1);
        int a = lact[b];
        int cnt = lact[b - 73] + lact[b - 72] + lact[b - 71]
                + lact[b - 1]  + a           + lact[b + 1]
                + lact[b + 71] + lact[b + 72] + lact[b + 73];
        lc8[li] = (uint8_t)(a | ((a && cnt >= 4) ? 2 : 0));  // MIN_SAMPLES=4 incl self
        lp[li] = li;
    }
    __syncthreads();
    if (tid < 256) {   // flags -> global, 16B per thread
        int row = tid >> 2, chunk = tid & 3;
        ((uint4*)(flags + (size_t)(r0 + row) * WW + c0))[chunk] =
            ((const uint4*)lc8)[row * 4 + chunk];
    }
    // union dedup (8-conn): W and N unconditional; NW only if !N && !W;
    // NE only if !N && !E. Covering unions (W-of-N at the N pixel, W-of-NE at
    // the NE pixel, N-of-E at the E pixel) are unconditional; union-find is
    // order-independent, so connectivity is preserved exactly.
    for (int li = tid; li < TILE; li += LTHREADS) {
        if (!(lc8[li] & 2)) continue;
        int lr = li >> 6, lc = li & 63;
        bool w = (lc > 0) && (lc8[li - 1] & 2);
        if (w) l_union(lp, li, li - 1);
        if (lr > 0) {
            bool n = (lc8[li - 64] & 2) != 0;
            if (n) {
                l_union(lp, li, li - 64);
            } else {
                if (!w && lc > 0 && (lc8[li - 65] & 2)) l_union(lp, li, li - 65);
                if (lc < 63 && !(lc8[li + 1] & 2) && (lc8[li - 63] & 2))
                    l_union(lp, li, li - 63);
            }
        }
    }
    __syncthreads();
    for (int li = tid; li < TILE; li += LTHREADS) {
        if (!(lc8[li] & 2)) continue;
        int root = li, p;
        while ((p = lp[root]) != root) root = p;   // lp stable after barrier
        int gi = (r0 + (li >> 6)) * WW + c0 + (li & 63);
        int gr = (r0 + (root >> 6)) * WW + c0 + (root & 63);
        parent[gi] = gr;
    }
}

// union only tile-crossing edges (R11-identical)
__global__ __launch_bounds__(THREADS) void k_merge(const uint8_t* __restrict__ flags,
                                                   int* __restrict__ parent) {
    int tile_x = blockIdx.x & 31, tile_y = blockIdx.x >> 5;
    int r0 = tile_y << 6, c0 = tile_x << 6;
    int t = threadIdx.x;
    int lane = t & 63;

    if (t < 64) {                                    // top row, lr=0, lc=t
        int r = r0, c = c0 + t, i = r * WW + c;
        bool selfC = (flags[i] & 2) != 0;
        bool nC = false, nwC = false, neC = false;
        if (selfC && r > 0) {
            nC  = (flags[i - WW] & 2) != 0;
            nwC = (c > 0)      && (flags[i - WW - 1] & 2);
            neC = (c < WW - 1) && (flags[i - WW + 1] & 2);
        }
        int did = 0, ra = -1, rb = -1;
        if (selfC && r > 0 && nC) { ra = uf_find(parent, i); rb = uf_find(parent, i - WW); did = 1; }
        int pra = __shfl_up(ra, 1), prb = __shfl_up(rb, 1), pdid = __shfl_up(did, 1);
        bool head = (lane == 0) || !pdid || pra != ra || prb != rb;
        if (did && head) uf_union(parent, ra, rb);
        if (selfC && r > 0) {
            if (t == 0) {
                if (nwC) uf_union(parent, i, i - WW - 1);          // diag tile
                if (!nC && neC) uf_union(parent, i, i - WW + 1);
            } else if (t == 63) {
                if (!nC && nwC) uf_union(parent, i, i - WW - 1);
                if (neC) {
                    bool eC = (c < WW - 1) && (flags[i + 1] & 2);
                    if (!eC) uf_union(parent, i, i - WW + 1);
                }
            } else if (!nC) {
                if (nwC) uf_union(parent, i, i - WW - 1);
                if (neC) uf_union(parent, i, i - WW + 1);
            }
        }
        if (t == 0 && selfC && c > 0 && (flags[i - 1] & 2))        // corner W edge
            uf_union(parent, i, i - 1);
    } else if (t < 127) {                            // left col, lr=1..63, lc=0
        int lr = t - 63;
        int r = r0 + lr, c = c0, i = r * WW + c;
        bool selfC = (flags[i] & 2) != 0;
        bool wC = false, nwC = false;
        if (selfC && c > 0) {
            wC  = (flags[i - 1] & 2) != 0;
            nwC = (flags[i - WW - 1] & 2) != 0;
        }
        int did = 0, ra = -1, rb = -1;
        if (selfC && wC) { ra = uf_find(parent, i); rb = uf_find(parent, i - 1); did = 1; }
        int pra = __shfl_up(ra, 1), prb = __shfl_up(rb, 1), pdid = __shfl_up(did, 1);
        bool head = (lane == 0) || !pdid || pra != ra || prb != rb;
        if (did && head) uf_union(parent, ra, rb);
        if (selfC && !wC && nwC) uf_union(parent, i, i - WW - 1);
    } else if (t < 190) {                            // right col, lr=1..63, lc=63
        int lr = t - 126;
        int r = r0 + lr, c = c0 + 63, i = r * WW + c;
        bool selfC = (flags[i] & 2) != 0;
        if (selfC && c < WW - 1) {
            bool neC = (flags[i - WW + 1] & 2) != 0;
            bool eC  = (flags[i + 1] & 2) != 0;
            if (neC && !eC) uf_union(parent, i, i - WW + 1);
        }
    }
}

// ---------------- border + stats with parent-value dedupe (R11-identical) ----------------
__device__ __forceinline__ void h_insert(int* h_key, int p) {
    unsigned slot = (((unsigned)p * 2654435761u) >> 20) & (HSZ - 1);
    for (;;) {
        int old = atomicCAS(&h_key[slot], -1, p);
        if (old == -1 || old == p) return;
        slot = (slot + 1) & (HSZ - 1);
    }
}
__device__ __forceinline__ int h_lookup(const int* h_key, const int* h_root, int p) {
    unsigned slot = (((unsigned)p * 2654435761u) >> 20) & (HSZ - 1);
    for (;;) {
        if (h_key[slot] == p) return h_root[slot];
        slot = (slot + 1) & (HSZ - 1);
    }
}

__global__ __launch_bounds__(THREADS) void k_border_stats(
        const uint8_t* __restrict__ flags, int* __restrict__ parent,
        int* __restrict__ labfull, int* __restrict__ sizes,
        unsigned long long* __restrict__ colsum,
        int* __restrict__ cand, int* __restrict__ counter) {
    __shared__ int h_key[HSZ];
    __shared__ int h_root[HSZ];
    __shared__ int s_lab[HSZ];
    __shared__ int s_sz[HSZ];
    __shared__ u64 s_cs[HSZ];
    for (int t = threadIdx.x; t < HSZ; t += THREADS) {
        h_key[t] = -1; s_lab[t] = -1; s_sz[t] = 0; s_cs[t] = 0;
    }
    __syncthreads();

    const int i = blockIdx.x * THREADS + threadIdx.x;
    const int f = flags[i];
    const int r = i >> 11, c = i & (WW - 1);

    int pself = -1;
    int pnb[8];
    #pragma unroll
    for (int t = 0; t < 8; ++t) pnb[t] = -1;

    if (f & 2) {
        pself = parent[i];                       // coalesced
        h_insert(h_key, pself);
    } else if (f & 1) {                          // active non-core
        const int dr8[8] = {-1,-1,-1, 0,0, 1,1,1};
        const int dc8[8] = {-1, 0, 1,-1,1,-1,0,1};
        #pragma unroll
        for (int t = 0; t < 8; ++t) {
            int rr = r + dr8[t], cc = c + dc8[t];
            if ((unsigned)rr < HH && (unsigned)cc < WW) {
                int n = rr * WW + cc;
                if (flags[n] & 2) {
                    int p = parent[n];
                    pnb[t] = p;
                    h_insert(h_key, p);
                }
            }
        }
    }
    __syncthreads();
    // resolve each distinct parent value once
    for (int t = threadIdx.x; t < HSZ; t += THREADS) {
        int k = h_key[t];
        if (k >= 0) h_root[t] = uf_find(parent, k);
    }
    __syncthreads();

    int lab = BIGL;
    if (f & 2) {
        lab = h_lookup(h_key, h_root, pself);
    } else if (f & 1) {
        int m = BIGL;
        #pragma unroll
        for (int t = 0; t < 8; ++t)
            if (pnb[t] >= 0) { int v = h_lookup(h_key, h_root, pnb[t]); if (v < m) m = v; }
        lab = m;                     // BIGL if no core neighbor
    }
    labfull[i] = lab;

    // wave-level run aggregation (WW % 64 == 0: wave never crosses a row)
    int lane = threadIdx.x & 63;
    int labp = __shfl_up(lab, 1);
    bool head = (lane == 0) || (labp != lab);
    unsigned long long hm = __ballot(head);
    if (head && lab < BIGL) {
        unsigned long long rest = (hm >> lane) >> 1;
        int len = rest ? __ffsll((unsigned long long)rest) : (64 - lane);
        long long cc0 = (long long)(i & (WW - 1));
        u64 csum = (u64)(cc0 * len + (long long)len * (len - 1) / 2);
        unsigned slot = (((unsigned)lab * 2654435761u) >> 20) & (HSZ - 1);
        for (;;) {
            int old = atomicCAS(&s_lab[slot], -1, lab);
            if (old == -1 || old == lab) {
                atomicAdd(&s_sz[slot], len);
                atomicAdd(&s_cs[slot], csum);
                break;
            }
            slot = (slot + 1) & (HSZ - 1);
        }
    }
    __syncthreads();
    for (int t = threadIdx.x; t < HSZ; t += THREADS) {
        int lb = s_lab[t];
        if (lb >= 0) {
            int add = s_sz[t];
            int old = atomicAdd(&sizes[lb], add);
            if (old < MINCL && old + add >= MINCL) {   // exactly one block sees this
                int p = atomicAdd(counter, 1);
                cand[p] = lb;
            }
            atomicAdd(&colsum[lb], s_cs[t]);
        }
    }
}

// ---- fused single-kernel top-26 selection (R11-identical) ----
__device__ __forceinline__ u64 wave_min_u64(u64 m) {
    #pragma unroll
    for (int off = 32; off; off >>= 1) {
        u64 o = __shfl_xor(m, off);
        if (o < m) m = o;
    }
    return m;
}

__global__ __launch_bounds__(THREADS) void k_sel(const int* __restrict__ cand,
                                                 int* __restrict__ counter,   // [0]=n, [1]=done
                                                 const int* __restrict__ sizes,
                                                 const unsigned long long* __restrict__ colsum,
                                                 unsigned long long* __restrict__ top26g,
                                                 signed char* __restrict__ chan) {
    __shared__ u64 wout[4 * NSLOTS];
    const int tid = threadIdx.x, lane = tid & 63, wv = tid >> 6;
    const int n = counter[0];
    int slice = (n + NB - 1) / NB;
    int j0 = blockIdx.x * slice;
    int j1 = j0 + slice; if (j1 > n) j1 = n;
    int len = j1 - j0; if (len < 0) len = 0;
    int chunk = (len + 3) >> 2;
    int s0 = j0 + wv * chunk;
    int s1 = s0 + chunk; if (s1 > j1) s1 = j1;

    u64 kk[3] = { ~0ull, ~0ull, ~0ull };
    #pragma unroll
    for (int t = 0; t < 3; ++t) {
        int j = s0 + lane + 64 * t;
        if (j < s1) {
            int lab = cand[j];
            float mean = (float)colsum[lab] / (float)sizes[lab];
            kk[t] = ((u64)__float_as_uint(mean) << 32) | (unsigned)lab;
        }
    }
    for (int k = 0; k < NSLOTS; ++k) {
        u64 m = kk[0]; int li = 0;
        if (kk[1] < m) { m = kk[1]; li = 1; }
        if (kk[2] < m) { m = kk[2]; li = 2; }
        u64 mpre = m;
        m = wave_min_u64(m);
        if (mpre == m && m != ~0ull) kk[li] = ~0ull;
        if (lane == 0) wout[wv * NSLOTS + k] = m;
    }
    __syncthreads();
    if (wv == 0) {
        u64 a = (lane < 4 * NSLOTS) ? wout[lane] : ~0ull;
        u64 b = (lane + 64 < 4 * NSLOTS) ? wout[lane + 64] : ~0ull;
        for (int k = 0; k < NSLOTS; ++k) {
            u64 m = a < b ? a : b; int li = a < b ? 0 : 1;
            u64 mpre = m;
            m = wave_min_u64(m);
            if (mpre == m && m != ~0ull) { if (li == 0) a = ~0ull; else b = ~0ull; }
            if (lane == 0) top26g[blockIdx.x * NSLOTS + k] = m;
        }
    }
    __syncthreads();
    __shared__ int lastflag;
    if (tid == 0) {
        __threadfence();
        lastflag = (atomicAdd(&counter[1], 1) == NB - 1);
    }
    __syncthreads();
    if (!lastflag) return;

    u64 mk[13];
    #pragma unroll
    for (int t = 0; t < 13; ++t) {
        int j = wv * 832 + lane + 64 * t;
        mk[t] = __hip_atomic_load(&top26g[j], __ATOMIC_RELAXED, __HIP_MEMORY_SCOPE_AGENT);
    }
    for (int k = 0; k < NSLOTS; ++k) {
        u64 m = mk[0]; int li = 0;
        #pragma unroll
        for (int t = 1; t < 13; ++t) if (mk[t] < m) { m = mk[t]; li = t; }
        u64 mpre = m;
        m = wave_min_u64(m);
        if (mpre == m && m != ~0ull) mk[li] = ~0ull;
        if (lane == 0) wout[wv * NSLOTS + k] = m;
    }
    __syncthreads();
    if (wv == 0) {
        u64 a = (lane < 4 * NSLOTS) ? wout[lane] : ~0ull;
        u64 b = (lane + 64 < 4 * NSLOTS) ? wout[lane + 64] : ~0ull;
        for (int k = 0; k < NSLOTS; ++k) {
            u64 m = a < b ? a : b; int li = a < b ? 0 : 1;
            u64 mpre = m;
            m = wave_min_u64(m);
            if (mpre == m && m != ~0ull) { if (li == 0) a = ~0ull; else b = ~0ull; }
            if (lane == 0 && m != ~0ull)
                chan[(unsigned int)(m & 0xFFFFFFFFull)] = (signed char)k;
        }
    }
}

// one-hot 26xHxW int32 output, non-temporal int4 stores (R11-identical)
__global__ __launch_bounds__(THREADS) void k_output(const int* __restrict__ labfull,
                                                    const signed char* __restrict__ chan,
                                                    int* __restrict__ out) {
    int i4 = (blockIdx.x * THREADS + threadIdx.x) * 4;
    int chv[4];
    #pragma unroll
    for (int t = 0; t < 4; ++t) {
        int lab = labfull[i4 + t];
        chv[t] = (lab < BIGL) ? (int)chan[lab] : -1;
    }
    #pragma unroll
    for (int c = 0; c < NSLOTS; ++c) {
        vi4 v;
        v.x = (chv[0] == c) ? 1 : 0;
        v.y = (chv[1] == c) ? 1 : 0;
        v.z = (chv[2] == c) ? 1 : 0;
        v.w = (chv[3] == c) ? 1 : 0;
        __builtin_nontemporal_store(v, (vi4*)(out + (size_t)c * HWN + i4));
    }
}

extern "C" void kernel_launch(void* const* d_in, const int* in_sizes, int n_in,
                              void* d_out, int out_size, void* d_ws, size_t ws_size,
                              hipStream_t stream) {
    const float* mask = (const float*)d_in[0];
    int* out = (int*)d_out;

    char* w = (char*)d_ws;
    int* parent                 = (int*)(w);                          //  8 MB
    int* labfull                = (int*)(w + (size_t)HWN * 4);        //  8 MB
    int* sizes                  = (int*)(w + (size_t)HWN * 8);        //  8 MB
    unsigned long long* colsum  = (unsigned long long*)(w + (size_t)HWN * 12); // 16 MB
    uint8_t* flags              = (uint8_t*)(w + (size_t)HWN * 20);   //  2 MB
    signed char* chan           = (signed char*)(w + (size_t)HWN * 21); // 2 MB
    int* cand                   = (int*)(w + (size_t)HWN * 22);       // 280 KB
    int* counter                = (int*)(w + (size_t)HWN * 22 + MAXCAND * 4);  // [0]=n,[1]=done
    unsigned long long* top26g  = (unsigned long long*)(w + (size_t)HWN * 22 + MAXCAND * 4 + 256);

    // no memsets: k_local zeros sizes/colsum/chan/counter/done
    const int blocks = HWN / THREADS;   // 8192
    k_local       <<<NTILES, LTHREADS, 0, stream>>>(mask, flags, parent,
                                                    sizes, colsum, chan, counter);
    k_merge       <<<NTILES, THREADS, 0, stream>>>(flags, parent);
    k_border_stats<<<blocks, THREADS, 0, stream>>>(flags, parent, labfull, sizes, colsum,
                                                   cand, counter);
    k_sel         <<<NB, THREADS, 0, stream>>>(cand, counter, sizes, colsum, top26g, chan);
    k_output      <<<HWN / (4 * THREADS), THREADS, 0, stream>>>(labfull, chan, out);
}

// Round 15
// 386.147 us; speedup vs baseline: 1.0524x; 1.0151x over previous
//
#include <hip/hip_runtime.h>
#include <stdint.h>

#define HH 1024
#define WW 2048
#define HWN (HH*WW)          // 2097152
#define BIGL HWN             // 'no cluster' sentinel
#define NSLOTS 26
#define MINCL 30
#define THREADS 256
#define LTHREADS 512         // k_local block size (8 waves)
#define MAXCAND 70000        // >= HWN/30 + 1
#define HSZ 512              // border_stats hash entries (256-pixel strip)
#define TILE 4096            // 64x64 tile
#define NTILES 512           // (1024/64)*(2048/64)
#define NB 128               // selection blocks

typedef int vi4 __attribute__((ext_vector_type(4)));
typedef unsigned long long u64;

// ---------------- global union-find (lock-free, min-root) ----------------
__device__ __forceinline__ int uf_load(int* p, int i) {
    return __hip_atomic_load(&p[i], __ATOMIC_RELAXED, __HIP_MEMORY_SCOPE_AGENT);
}
__device__ __forceinline__ void uf_store(int* p, int i, int v) {
    __hip_atomic_store(&p[i], v, __ATOMIC_RELAXED, __HIP_MEMORY_SCOPE_AGENT);
}
__device__ int uf_find(int* parent, int x) {
    int p = uf_load(parent, x);
    while (p != x) {
        int gp = uf_load(parent, p);
        if (gp != p) uf_store(parent, x, gp);   // path halving (benign race)
        x = p; p = gp;
    }
    return p;
}
__device__ void uf_union(int* parent, int a, int b) {
    int ra = uf_find(parent, a);
    int rb = uf_find(parent, b);
    while (ra != rb) {
        if (ra > rb) { int t = ra; ra = rb; rb = t; }   // hook larger under smaller
        int old = atomicCAS(&parent[rb], rb, ra);
        if (old == rb) return;
        rb = uf_find(parent, old);
        ra = uf_find(parent, ra);
    }
}

// ---------------- LDS union-find (block-local, min-root) ----------------
__device__ __forceinline__ int l_load(int* p, int i) {
    return __hip_atomic_load(&p[i], __ATOMIC_RELAXED, __HIP_MEMORY_SCOPE_WORKGROUP);
}
__device__ __forceinline__ void l_store(int* p, int i, int v) {
    __hip_atomic_store(&p[i], v, __ATOMIC_RELAXED, __HIP_MEMORY_SCOPE_WORKGROUP);
}
__device__ int l_find(int* lp, int x) {
    int p = l_load(lp, x);
    while (p != x) {
        int gp = l_load(lp, p);
        if (gp != p) l_store(lp, x, gp);
        x = p; p = gp;
    }
    return p;
}
__device__ void l_union(int* lp, int a, int b) {
    int ra = l_find(lp, a);
    int rb = l_find(lp, b);
    while (ra != rb) {
        if (ra > rb) { int t = ra; ra = rb; rb = t; }
        int old = atomicCAS(&lp[rb], rb, ra);
        if (old == rb) return;
        rb = l_find(lp, old);
        ra = l_find(lp, ra);
    }
}

// ---------------- fused init + per-tile CC + ws zeroing ----------------
// parent[] is self-describing: -1 for non-core, global tile-root for core.
__global__ __launch_bounds__(LTHREADS) void k_local(const float* __restrict__ mask,
                                                    uint8_t* __restrict__ flags,
                                                    int* __restrict__ parent,
                                                    int* __restrict__ sizes,
                                                    unsigned long long* __restrict__ colsum,
                                                    signed char* __restrict__ chan,
                                                    int* __restrict__ counter) {
    __shared__ uint8_t lact[66 * 72];   // halo active map, row stride 72
    __shared__ uint8_t lc8[TILE];
    __shared__ int lp[TILE];
    const int tid = threadIdx.x;
    int tile_x = blockIdx.x & 31, tile_y = blockIdx.x >> 5;
    int r0 = tile_y << 6, c0 = tile_x << 6;

    {   // zero this block's 1/512 slice of sizes/colsum/chan (+counter/done once)
        int base = blockIdx.x * (HWN / NTILES);      // 4096 elements
        vi4* sz4 = (vi4*)(sizes + base);
        vi4* cs4 = (vi4*)(colsum + base);
        for (int t = tid; t < 1024; t += LTHREADS) sz4[t] = (vi4)0;
        for (int t = tid; t < 2048; t += LTHREADS) cs4[t] = (vi4)0;
        vi4* ch4 = (vi4*)(chan + base);
        for (int t = tid; t < 256; t += LTHREADS) ch4[t] = (vi4)(-1);
        if (blockIdx.x == 0 && tid == 0) { counter[0] = 0; counter[1] = 0; }
    }

    {   // body rows: 64 rows x 16 float4, coalesced; 512 threads -> 2 passes
        int lr = tid >> 4, q = tid & 15;
        #pragma unroll
        for (int pass = 0; pass < 2; ++pass) {
            int rr = lr + pass * 32;
            const float4* src = (const float4*)(mask + (size_t)(r0 + rr) * WW + c0);
            float4 v = src[q];
            uint8_t* dst = &lact[(rr + 1) * 72 + (q * 4 + 1)];
            dst[0] = v.x > 0.1f; dst[1] = v.y > 0.1f;
            dst[2] = v.z > 0.1f; dst[3] = v.w > 0.1f;
        }
    }
    if (tid < 32) {          // halo top/bottom rows (cols 1..64)
        int q = tid & 15;
        bool top = tid < 16;
        int gr = top ? r0 - 1 : r0 + 64;
        int yy = top ? 0 : 65;
        uint8_t* dst = &lact[yy * 72 + (q * 4 + 1)];
        if ((unsigned)gr < HH) {
            const float4* src = (const float4*)(mask + (size_t)gr * WW + c0);
            float4 v = src[q];
            dst[0] = v.x > 0.1f; dst[1] = v.y > 0.1f;
            dst[2] = v.z > 0.1f; dst[3] = v.w > 0.1f;
        } else {
            dst[0] = 0; dst[1] = 0; dst[2] = 0; dst[3] = 0;
        }
    } else if (tid >= 64 && tid < 64 + 132) {   // halo cols incl corners
        int lane = tid - 64;                    // 0..131
        int side = lane >= 66;                  // 0=left(c0-1), 1=right(c0+64)
        int yy = side ? lane - 66 : lane;       // 0..65
        int gr = r0 - 1 + yy;
        int gc = side ? c0 + 64 : c0 - 1;
        bool a = false;
        if ((unsigned)gr < HH && (unsigned)gc < WW) a = mask[(size_t)gr * WW + gc] > 0.1f;
        lact[yy * 72 + (side ? 65 : 0)] = a ? 1 : 0;
    }
    __syncthreads();
    for (int li = tid; li < TILE; li += LTHREADS) {
        int lr = li >> 6, lc = li & 63;
        int b = (lr + 1) * 72 + (lc + 1);
        int a = lact[b];
        int cnt = lact[b - 73] + lact[b - 72] + lact[b - 71]
                + lact[b - 1]  + a           + lact[b + 1]
                + lact[b + 71] + lact[b + 72] + lact[b + 73];
        lc8[li] = (uint8_t)(a | ((a && cnt >= 4) ? 2 : 0));  // MIN_SAMPLES=4 incl self
        lp[li] = li;
    }
    __syncthreads();
    if (tid < 256) {   // flags -> global, 16B per thread
        int row = tid >> 2, chunk = tid & 3;
        ((uint4*)(flags + (size_t)(r0 + row) * WW + c0))[chunk] =
            ((const uint4*)lc8)[row * 4 + chunk];
    }
    // union dedup (8-conn): W and N unconditional; NW only if !N && !W;
    // NE only if !N && !E (covering unions are unconditional; order-independent)
    for (int li = tid; li < TILE; li += LTHREADS) {
        if (!(lc8[li] & 2)) continue;
        int lr = li >> 6, lc = li & 63;
        bool w = (lc > 0) && (lc8[li - 1] & 2);
        if (w) l_union(lp, li, li - 1);
        if (lr > 0) {
            bool n = (lc8[li - 64] & 2) != 0;
            if (n) {
                l_union(lp, li, li - 64);
            } else {
                if (!w && lc > 0 && (lc8[li - 65] & 2)) l_union(lp, li, li - 65);
                if (lc < 63 && !(lc8[li + 1] & 2) && (lc8[li - 63] & 2))
                    l_union(lp, li, li - 63);
            }
        }
    }
    __syncthreads();
    // write parent for ALL pixels: core -> global root, non-core -> -1
    for (int li = tid; li < TILE; li += LTHREADS) {
        int v = -1;
        if (lc8[li] & 2) {
            int root = li, p;
            while ((p = lp[root]) != root) root = p;   // lp stable after barrier
            v = (r0 + (root >> 6)) * WW + c0 + (root & 63);
        }
        int gi = (r0 + (li >> 6)) * WW + c0 + (li & 63);
        parent[gi] = v;
    }
}

// union only tile-crossing edges (R14-identical)
__global__ __launch_bounds__(THREADS) void k_merge(const uint8_t* __restrict__ flags,
                                                   int* __restrict__ parent) {
    int tile_x = blockIdx.x & 31, tile_y = blockIdx.x >> 5;
    int r0 = tile_y << 6, c0 = tile_x << 6;
    int t = threadIdx.x;
    int lane = t & 63;

    if (t < 64) {                                    // top row, lr=0, lc=t
        int r = r0, c = c0 + t, i = r * WW + c;
        bool selfC = (flags[i] & 2) != 0;
        bool nC = false, nwC = false, neC = false;
        if (selfC && r > 0) {
            nC  = (flags[i - WW] & 2) != 0;
            nwC = (c > 0)      && (flags[i - WW - 1] & 2);
            neC = (c < WW - 1) && (flags[i - WW + 1] & 2);
        }
        int did = 0, ra = -1, rb = -1;
        if (selfC && r > 0 && nC) { ra = uf_find(parent, i); rb = uf_find(parent, i - WW); did = 1; }
        int pra = __shfl_up(ra, 1), prb = __shfl_up(rb, 1), pdid = __shfl_up(did, 1);
        bool head = (lane == 0) || !pdid || pra != ra || prb != rb;
        if (did && head) uf_union(parent, ra, rb);
        if (selfC && r > 0) {
            if (t == 0) {
                if (nwC) uf_union(parent, i, i - WW - 1);          // diag tile
                if (!nC && neC) uf_union(parent, i, i - WW + 1);
            } else if (t == 63) {
                if (!nC && nwC) uf_union(parent, i, i - WW - 1);
                if (neC) {
                    bool eC = (c < WW - 1) && (flags[i + 1] & 2);
                    if (!eC) uf_union(parent, i, i - WW + 1);
                }
            } else if (!nC) {
                if (nwC) uf_union(parent, i, i - WW - 1);
                if (neC) uf_union(parent, i, i - WW + 1);
            }
        }
        if (t == 0 && selfC && c > 0 && (flags[i - 1] & 2))        // corner W edge
            uf_union(parent, i, i - 1);
    } else if (t < 127) {                            // left col, lr=1..63, lc=0
        int lr = t - 63;
        int r = r0 + lr, c = c0, i = r * WW + c;
        bool selfC = (flags[i] & 2) != 0;
        bool wC = false, nwC = false;
        if (selfC && c > 0) {
            wC  = (flags[i - 1] & 2) != 0;
            nwC = (flags[i - WW - 1] & 2) != 0;
        }
        int did = 0, ra = -1, rb = -1;
        if (selfC && wC) { ra = uf_find(parent, i); rb = uf_find(parent, i - 1); did = 1; }
        int pra = __shfl_up(ra, 1), prb = __shfl_up(rb, 1), pdid = __shfl_up(did, 1);
        bool head = (lane == 0) || !pdid || pra != ra || prb != rb;
        if (did && head) uf_union(parent, ra, rb);
        if (selfC && !wC && nwC) uf_union(parent, i, i - WW - 1);
    } else if (t < 190) {                            // right col, lr=1..63, lc=63
        int lr = t - 126;
        int r = r0 + lr, c = c0 + 63, i = r * WW + c;
        bool selfC = (flags[i] & 2) != 0;
        if (selfC && c < WW - 1) {
            bool neC = (flags[i - WW + 1] & 2) != 0;
            bool eC  = (flags[i + 1] & 2) != 0;
            if (neC && !eC) uf_union(parent, i, i - WW + 1);
        }
    }
}

// ---------------- border + stats: parent[] is self-describing ----------------
// Border pixels read parent[n] directly (>=0 iff core) — no flags[n] probe,
// no dependent second load. Distinct parent values deduped via LDS hash ->
// one uf_find per distinct value per block.
__device__ __forceinline__ void h_insert(int* h_key, int p) {
    unsigned slot = (((unsigned)p * 2654435761u) >> 20) & (HSZ - 1);
    for (;;) {
        int old = atomicCAS(&h_key[slot], -1, p);
        if (old == -1 || old == p) return;
        slot = (slot + 1) & (HSZ - 1);
    }
}
__device__ __forceinline__ int h_lookup(const int* h_key, const int* h_root, int p) {
    unsigned slot = (((unsigned)p * 2654435761u) >> 20) & (HSZ - 1);
    for (;;) {
        if (h_key[slot] == p) return h_root[slot];
        slot = (slot + 1) & (HSZ - 1);
    }
}

__global__ __launch_bounds__(THREADS) void k_border_stats(
        const uint8_t* __restrict__ flags, int* __restrict__ parent,
        int* __restrict__ labfull, int* __restrict__ sizes,
        unsigned long long* __restrict__ colsum,
        int* __restrict__ cand, int* __restrict__ counter) {
    __shared__ int h_key[HSZ];
    __shared__ int h_root[HSZ];
    __shared__ int s_lab[HSZ];
    __shared__ int s_sz[HSZ];
    __shared__ u64 s_cs[HSZ];
    for (int t = threadIdx.x; t < HSZ; t += THREADS) {
        h_key[t] = -1; s_lab[t] = -1; s_sz[t] = 0; s_cs[t] = 0;
    }
    __syncthreads();

    const int i = blockIdx.x * THREADS + threadIdx.x;
    const int f = flags[i];
    const int r = i >> 11, c = i & (WW - 1);

    int pself = -1;
    int pnb[8];
    #pragma unroll
    for (int t = 0; t < 8; ++t) pnb[t] = -1;

    if (f & 2) {
        pself = parent[i];                       // coalesced, >=0
        h_insert(h_key, pself);
    } else if (f & 1) {                          // active non-core
        const int dr8[8] = {-1,-1,-1, 0,0, 1,1,1};
        const int dc8[8] = {-1, 0, 1,-1,1,-1,0,1};
        #pragma unroll
        for (int t = 0; t < 8; ++t) {
            int rr = r + dr8[t], cc = c + dc8[t];
            if ((unsigned)rr < HH && (unsigned)cc < WW) {
                int p = parent[rr * WW + cc];    // single load; >=0 iff core
                pnb[t] = p;
                if (p >= 0) h_insert(h_key, p);
            }
        }
    }
    __syncthreads();
    // resolve each distinct parent value once
    for (int t = threadIdx.x; t < HSZ; t += THREADS) {
        int k = h_key[t];
        if (k >= 0) h_root[t] = uf_find(parent, k);
    }
    __syncthreads();

    int lab = BIGL;
    if (f & 2) {
        lab = h_lookup(h_key, h_root, pself);
    } else if (f & 1) {
        int m = BIGL;
        #pragma unroll
        for (int t = 0; t < 8; ++t)
            if (pnb[t] >= 0) { int v = h_lookup(h_key, h_root, pnb[t]); if (v < m) m = v; }
        lab = m;                     // BIGL if no core neighbor
    }
    labfull[i] = lab;

    // wave-level run aggregation (WW % 64 == 0: wave never crosses a row)
    int lane = threadIdx.x & 63;
    int labp = __shfl_up(lab, 1);
    bool head = (lane == 0) || (labp != lab);
    unsigned long long hm = __ballot(head);
    if (head && lab < BIGL) {
        unsigned long long rest = (hm >> lane) >> 1;
        int len = rest ? __ffsll((unsigned long long)rest) : (64 - lane);
        long long cc0 = (long long)(i & (WW - 1));
        u64 csum = (u64)(cc0 * len + (long long)len * (len - 1) / 2);
        unsigned slot = (((unsigned)lab * 2654435761u) >> 20) & (HSZ - 1);
        for (;;) {
            int old = atomicCAS(&s_lab[slot], -1, lab);
            if (old == -1 || old == lab) {
                atomicAdd(&s_sz[slot], len);
                atomicAdd(&s_cs[slot], csum);
                break;
            }
            slot = (slot + 1) & (HSZ - 1);
        }
    }
    __syncthreads();
    for (int t = threadIdx.x; t < HSZ; t += THREADS) {
        int lb = s_lab[t];
        if (lb >= 0) {
            int add = s_sz[t];
            int old = atomicAdd(&sizes[lb], add);
            if (old < MINCL && old + add >= MINCL) {   // exactly one block sees this
                int p = atomicAdd(counter, 1);
                cand[p] = lb;
            }
            atomicAdd(&colsum[lb], s_cs[t]);
        }
    }
}

// ---- fused single-kernel top-26 selection (R14-identical) ----
__device__ __forceinline__ u64 wave_min_u64(u64 m) {
    #pragma unroll
    for (int off = 32; off; off >>= 1) {
        u64 o = __shfl_xor(m, off);
        if (o < m) m = o;
    }
    return m;
}

__global__ __launch_bounds__(THREADS) void k_sel(const int* __restrict__ cand,
                                                 int* __restrict__ counter,   // [0]=n, [1]=done
                                                 const int* __restrict__ sizes,
                                                 const unsigned long long* __restrict__ colsum,
                                                 unsigned long long* __restrict__ top26g,
                                                 signed char* __restrict__ chan) {
    __shared__ u64 wout[4 * NSLOTS];
    const int tid = threadIdx.x, lane = tid & 63, wv = tid >> 6;
    const int n = counter[0];
    int slice = (n + NB - 1) / NB;
    int j0 = blockIdx.x * slice;
    int j1 = j0 + slice; if (j1 > n) j1 = n;
    int len = j1 - j0; if (len < 0) len = 0;
    int chunk = (len + 3) >> 2;
    int s0 = j0 + wv * chunk;
    int s1 = s0 + chunk; if (s1 > j1) s1 = j1;

    u64 kk[3] = { ~0ull, ~0ull, ~0ull };
    #pragma unroll
    for (int t = 0; t < 3; ++t) {
        int j = s0 + lane + 64 * t;
        if (j < s1) {
            int lab = cand[j];
            float mean = (float)colsum[lab] / (float)sizes[lab];
            kk[t] = ((u64)__float_as_uint(mean) << 32) | (unsigned)lab;
        }
    }
    for (int k = 0; k < NSLOTS; ++k) {
        u64 m = kk[0]; int li = 0;
        if (kk[1] < m) { m = kk[1]; li = 1; }
        if (kk[2] < m) { m = kk[2]; li = 2; }
        u64 mpre = m;
        m = wave_min_u64(m);
        if (mpre == m && m != ~0ull) kk[li] = ~0ull;
        if (lane == 0) wout[wv * NSLOTS + k] = m;
    }
    __syncthreads();
    if (wv == 0) {
        u64 a = (lane < 4 * NSLOTS) ? wout[lane] : ~0ull;
        u64 b = (lane + 64 < 4 * NSLOTS) ? wout[lane + 64] : ~0ull;
        for (int k = 0; k < NSLOTS; ++k) {
            u64 m = a < b ? a : b; int li = a < b ? 0 : 1;
            u64 mpre = m;
            m = wave_min_u64(m);
            if (mpre == m && m != ~0ull) { if (li == 0) a = ~0ull; else b = ~0ull; }
            if (lane == 0) top26g[blockIdx.x * NSLOTS + k] = m;
        }
    }
    __syncthreads();
    __shared__ int lastflag;
    if (tid == 0) {
        __threadfence();
        lastflag = (atomicAdd(&counter[1], 1) == NB - 1);
    }
    __syncthreads();
    if (!lastflag) return;

    u64 mk[13];
    #pragma unroll
    for (int t = 0; t < 13; ++t) {
        int j = wv * 832 + lane + 64 * t;
        mk[t] = __hip_atomic_load(&top26g[j], __ATOMIC_RELAXED, __HIP_MEMORY_SCOPE_AGENT);
    }
    for (int k = 0; k < NSLOTS; ++k) {
        u64 m = mk[0]; int li = 0;
        #pragma unroll
        for (int t = 1; t < 13; ++t) if (mk[t] < m) { m = mk[t]; li = t; }
        u64 mpre = m;
        m = wave_min_u64(m);
        if (mpre == m && m != ~0ull) mk[li] = ~0ull;
        if (lane == 0) wout[wv * NSLOTS + k] = m;
    }
    __syncthreads();
    if (wv == 0) {
        u64 a = (lane < 4 * NSLOTS) ? wout[lane] : ~0ull;
        u64 b = (lane + 64 < 4 * NSLOTS) ? wout[lane + 64] : ~0ull;
        for (int k = 0; k < NSLOTS; ++k) {
            u64 m = a < b ? a : b; int li = a < b ? 0 : 1;
            u64 mpre = m;
            m = wave_min_u64(m);
            if (mpre == m && m != ~0ull) { if (li == 0) a = ~0ull; else b = ~0ull; }
            if (lane == 0 && m != ~0ull)
                chan[(unsigned int)(m & 0xFFFFFFFFull)] = (signed char)k;
        }
    }
}

// one-hot 26xHxW int32 output, non-temporal int4 stores (R14-identical)
__global__ __launch_bounds__(THREADS) void k_output(const int* __restrict__ labfull,
                                                    const signed char* __restrict__ chan,
                                                    int* __restrict__ out) {
    int i4 = (blockIdx.x * THREADS + threadIdx.x) * 4;
    int chv[4];
    #pragma unroll
    for (int t = 0; t < 4; ++t) {
        int lab = labfull[i4 + t];
        chv[t] = (lab < BIGL) ? (int)chan[lab] : -1;
    }
    #pragma unroll
    for (int c = 0; c < NSLOTS; ++c) {
        vi4 v;
        v.x = (chv[0] == c) ? 1 : 0;
        v.y = (chv[1] == c) ? 1 : 0;
        v.z = (chv[2] == c) ? 1 : 0;
        v.w = (chv[3] == c) ? 1 : 0;
        __builtin_nontemporal_store(v, (vi4*)(out + (size_t)c * HWN + i4));
    }
}

extern "C" void kernel_launch(void* const* d_in, const int* in_sizes, int n_in,
                              void* d_out, int out_size, void* d_ws, size_t ws_size,
                              hipStream_t stream) {
    const float* mask = (const float*)d_in[0];
    int* out = (int*)d_out;

    char* w = (char*)d_ws;
    int* parent                 = (int*)(w);                          //  8 MB
    int* labfull                = (int*)(w + (size_t)HWN * 4);        //  8 MB
    int* sizes                  = (int*)(w + (size_t)HWN * 8);        //  8 MB
    unsigned long long* colsum  = (unsigned long long*)(w + (size_t)HWN * 12); // 16 MB
    uint8_t* flags              = (uint8_t*)(w + (size_t)HWN * 20);   //  2 MB
    signed char* chan           = (signed char*)(w + (size_t)HWN * 21); // 2 MB
    int* cand                   = (int*)(w + (size_t)HWN * 22);       // 280 KB
    int* counter                = (int*)(w + (size_t)HWN * 22 + MAXCAND * 4);  // [0]=n,[1]=done
    unsigned long long* top26g  = (unsigned long long*)(w + (size_t)HWN * 22 + MAXCAND * 4 + 256);

    // no memsets: k_local zeros sizes/colsum/chan/counter/done
    const int blocks = HWN / THREADS;   // 8192
    k_local       <<<NTILES, LTHREADS, 0, stream>>>(mask, flags, parent,
                                                    sizes, colsum, chan, counter);
    k_merge       <<<NTILES, THREADS, 0, stream>>>(flags, parent);
    k_border_stats<<<blocks, THREADS, 0, stream>>>(flags, parent, labfull, sizes, colsum,
                                                   cand, counter);
    k_sel         <<<NB, THREADS, 0, stream>>>(cand, counter, sizes, colsum, top26g, chan);
    k_output      <<<HWN / (4 * THREADS), THREADS, 0, stream>>>(labfull, chan, out);
}